// Round 1
// baseline (1221.766 us; speedup 1.0000x reference)
//
#include <hip/hip_runtime.h>

#define NN 100000
#define NE 1600000
#define H  128
#define NG 512
#define NC 10

// ---------------------------------------------------------------- utilities
__device__ __forceinline__ int lower_bound_i(const int* __restrict__ a, int n, int val) {
    int lo = 0, hi = n;
    while (lo < hi) {
        int mid = (lo + hi) >> 1;
        if (a[mid] < val) lo = mid + 1; else hi = mid;
    }
    return lo;
}

// ---------------------------------------------------------------- degree histogram
__global__ __launch_bounds__(256) void deg_kernel(const int* __restrict__ dst,
                                                  int* __restrict__ deg) {
    int e = blockIdx.x * 256 + threadIdx.x;
    if (e < NE) atomicAdd(&deg[dst[e]], 1);
}

__global__ __launch_bounds__(256) void dis_kernel(const int* __restrict__ deg,
                                                  float* __restrict__ dis) {
    int i = blockIdx.x * 256 + threadIdx.x;
    if (i < NN) dis[i] = rsqrtf((float)deg[i] + 1.0f);
}

// single-block exclusive scan of deg -> offs (N+1) and cursor copy
__global__ __launch_bounds__(1024) void scan_kernel(const int* __restrict__ deg,
                                                    int* __restrict__ offs,
                                                    int* __restrict__ cursor) {
    __shared__ int wsum[16];
    __shared__ int carry_s;
    int t = threadIdx.x;
    int lane = t & 63, wid = t >> 6;
    if (t == 0) carry_s = 0;
    __syncthreads();
    for (int base = 0; base < NN; base += 1024) {
        int i = base + t;
        int v = (i < NN) ? deg[i] : 0;
        int incl = v;
        #pragma unroll
        for (int d = 1; d < 64; d <<= 1) {
            int u = __shfl_up(incl, d, 64);
            if (lane >= d) incl += u;
        }
        if (lane == 63) wsum[wid] = incl;
        __syncthreads();                      // A: wsum visible, prev carry_s stable
        int wpre = 0;
        for (int w = 0; w < wid; ++w) wpre += wsum[w];
        int carry = carry_s;
        int excl = carry + wpre + incl - v;
        if (i < NN) { offs[i] = excl; cursor[i] = excl; }
        __syncthreads();                      // B: everyone done reading carry_s
        if (t == 1023) carry_s = carry + wpre + incl;
        __syncthreads();                      // C: new carry_s visible
    }
    if (t == 0) offs[NN] = carry_s;
}

// bucket edges by dst; store src index and full edge coefficient
__global__ __launch_bounds__(256) void scatter_kernel(const int* __restrict__ src,
                                                      const int* __restrict__ dst,
                                                      const float* __restrict__ dis,
                                                      int* __restrict__ cursor,
                                                      int* __restrict__ ssrc,
                                                      float* __restrict__ scoef) {
    int e = blockIdx.x * 256 + threadIdx.x;
    if (e < NE) {
        int s = src[e], d = dst[e];
        int pos = atomicAdd(&cursor[d], 1);
        ssrc[pos] = s;
        scoef[pos] = dis[s] * dis[d];
    }
}

// ---------------------------------------------------------------- GEMM: hw = (in0 [+ in1]) @ W
// tile: 64 rows x 128 cols, k-chunks of 32. 256 threads: tx=t&15 (8 cols), ty=t>>4 (4 rows)
__global__ __launch_bounds__(256) void gemm_kernel(const float* __restrict__ in0,
                                                   const float* __restrict__ in1,
                                                   const float* __restrict__ W,
                                                   float* __restrict__ hw) {
    __shared__ float sIn[64 * 33];       // padded stride 33: bank-conflict-free
    __shared__ float sW[32 * H];
    int t  = threadIdx.x;
    int tx = t & 15, ty = t >> 4;
    int row0 = blockIdx.x * 64;
    float acc[4][8];
    #pragma unroll
    for (int r = 0; r < 4; ++r)
        #pragma unroll
        for (int c = 0; c < 8; ++c) acc[r][c] = 0.f;

    for (int k0 = 0; k0 < H; k0 += 32) {
        __syncthreads();
        // stage input tile 64x32 (scalar, coalesced in global, conflict-free in LDS)
        #pragma unroll
        for (int i = 0; i < 8; ++i) {
            int f   = t + i * 256;
            int col = f & 31;
            int row = f >> 5;
            int grow = row0 + row;
            float v = 0.f;
            if (grow < NN) {
                v = in0[grow * H + k0 + col];
                if (in1) v += in1[grow * H + k0 + col];
            }
            sIn[row * 33 + col] = v;
        }
        // stage W chunk 32x128 (float4, coalesced)
        #pragma unroll
        for (int i = 0; i < 4; ++i) {
            int g    = t + i * 256;
            int row  = g >> 5;
            int col  = (g & 31) << 2;
            *(float4*)&sW[row * H + col] = *(const float4*)&W[(k0 + row) * H + col];
        }
        __syncthreads();
        #pragma unroll
        for (int kk = 0; kk < 32; ++kk) {
            const float* wrow = &sW[kk * H + tx * 8];
            float4 w0 = *(const float4*)wrow;
            float4 w1 = *(const float4*)(wrow + 4);
            #pragma unroll
            for (int rr = 0; rr < 4; ++rr) {
                float a = sIn[(ty * 4 + rr) * 33 + kk];
                acc[rr][0] += a * w0.x; acc[rr][1] += a * w0.y;
                acc[rr][2] += a * w0.z; acc[rr][3] += a * w0.w;
                acc[rr][4] += a * w1.x; acc[rr][5] += a * w1.y;
                acc[rr][6] += a * w1.z; acc[rr][7] += a * w1.w;
            }
        }
    }
    #pragma unroll
    for (int rr = 0; rr < 4; ++rr) {
        int grow = row0 + ty * 4 + rr;
        if (grow < NN) {
            float4 o0 = make_float4(acc[rr][0], acc[rr][1], acc[rr][2], acc[rr][3]);
            float4 o1 = make_float4(acc[rr][4], acc[rr][5], acc[rr][6], acc[rr][7]);
            *(float4*)&hw[grow * H + tx * 8]     = o0;
            *(float4*)&hw[grow * H + tx * 8 + 4] = o1;
        }
    }
}

// ---------------------------------------------------------------- aggregation
// one wave per node; lane owns 2 features (float2). out = relu(sum_e coef*hw[src] + sc*hw[i] + b)
__global__ __launch_bounds__(256) void agg_kernel(const float* __restrict__ hw,
                                                  const float* __restrict__ dis,
                                                  const int* __restrict__ offs,
                                                  const int* __restrict__ ssrc,
                                                  const float* __restrict__ scoef,
                                                  const float* __restrict__ bias,
                                                  float* __restrict__ outh) {
    int wid  = threadIdx.x >> 6;
    int lane = threadIdx.x & 63;
    int node = blockIdx.x * 4 + wid;
    if (node >= NN) return;
    int beg = offs[node], end = offs[node + 1];
    int j = lane * 2;
    float a0 = 0.f, a1 = 0.f;
    int k = beg;
    for (; k + 2 <= end; k += 2) {
        int   s0 = ssrc[k],     s1 = ssrc[k + 1];
        float c0 = scoef[k],    c1 = scoef[k + 1];
        float2 v0 = *(const float2*)&hw[s0 * H + j];
        float2 v1 = *(const float2*)&hw[s1 * H + j];
        a0 += c0 * v0.x + c1 * v1.x;
        a1 += c0 * v0.y + c1 * v1.y;
    }
    if (k < end) {
        int s = ssrc[k]; float c = scoef[k];
        float2 v = *(const float2*)&hw[s * H + j];
        a0 += c * v.x; a1 += c * v.y;
    }
    float dv = dis[node];
    float sc = dv * dv;
    float2 hv = *(const float2*)&hw[node * H + j];
    float r0 = a0 + sc * hv.x + bias[j];
    float r1 = a1 + sc * hv.y + bias[j + 1];
    r0 = fmaxf(r0, 0.f);
    r1 = fmaxf(r1, 0.f);
    *(float2*)&outh[node * H + j] = make_float2(r0, r1);
}

// ---------------------------------------------------------------- mean-pool + linear head
__global__ __launch_bounds__(128) void pool_kernel(const float* __restrict__ h,
                                                   const int* __restrict__ batch,
                                                   const float* __restrict__ linW,
                                                   const float* __restrict__ linb,
                                                   float* __restrict__ out) {
    __shared__ float pld[H];
    int g = blockIdx.x;
    int t = threadIdx.x;
    int lo = lower_bound_i(batch, NN, g);
    int hi = lower_bound_i(batch, NN, g + 1);
    float sum = 0.f;
    for (int n = lo; n < hi; ++n) sum += h[n * H + t];
    float cnt = (float)(hi - lo);
    pld[t] = sum / fmaxf(cnt, 1.0f);
    __syncthreads();
    if (t < NC) {
        float acc = linb[t];
        #pragma unroll 4
        for (int j = 0; j < H; ++j) acc += pld[j] * linW[j * NC + t];
        out[g * NC + t] = acc;
    }
}

// ---------------------------------------------------------------- launch
extern "C" void kernel_launch(void* const* d_in, const int* in_sizes, int n_in,
                              void* d_out, int out_size, void* d_ws, size_t ws_size,
                              hipStream_t stream) {
    const float* x     = (const float*)d_in[0];
    const int*   ei    = (const int*)d_in[1];   // [2][NE]
    const int*   batch = (const int*)d_in[2];
    const float* W0    = (const float*)d_in[3];
    const float* b0    = (const float*)d_in[4];
    const float* Ws    = (const float*)d_in[5]; // [3][H][H]
    const float* bs    = (const float*)d_in[6]; // [3][H]
    const float* linW  = (const float*)d_in[7];
    const float* linb  = (const float*)d_in[8];
    const int* src = ei;
    const int* dst = ei + NE;

    char* p = (char*)d_ws;
    auto alloc = [&](size_t bytes) -> void* {
        void* r = (void*)p;
        p += (bytes + 255) & ~(size_t)255;
        return r;
    };
    float* buf0   = (float*)alloc((size_t)NN * H * 4);
    float* buf1   = (float*)alloc((size_t)NN * H * 4);
    float* buf2   = (float*)alloc((size_t)NN * H * 4);
    float* hwb    = (float*)alloc((size_t)NN * H * 4);
    float* dis    = (float*)alloc((size_t)NN * 4);
    int*   deg    = (int*)alloc((size_t)NN * 4);
    int*   offs   = (int*)alloc((size_t)(NN + 1) * 4);
    int*   cursor = (int*)alloc((size_t)NN * 4);
    int*   ssrc   = (int*)alloc((size_t)NE * 4);
    float* scoef  = (float*)alloc((size_t)NE * 4);

    hipMemsetAsync(deg, 0, (size_t)NN * 4, stream);

    deg_kernel<<<(NE + 255) / 256, 256, 0, stream>>>(dst, deg);
    dis_kernel<<<(NN + 255) / 256, 256, 0, stream>>>(deg, dis);
    scan_kernel<<<1, 1024, 0, stream>>>(deg, offs, cursor);
    scatter_kernel<<<(NE + 255) / 256, 256, 0, stream>>>(src, dst, dis, cursor, ssrc, scoef);

    int gemm_grid = (NN + 63) / 64;
    int agg_grid  = (NN + 3) / 4;

    // layer 0: in = x
    gemm_kernel<<<gemm_grid, 256, 0, stream>>>(x, nullptr, W0, hwb);
    agg_kernel<<<agg_grid, 256, 0, stream>>>(hwb, dis, offs, ssrc, scoef, b0, buf0);
    // layer 1: in = h0
    gemm_kernel<<<gemm_grid, 256, 0, stream>>>(buf0, nullptr, Ws, hwb);
    agg_kernel<<<agg_grid, 256, 0, stream>>>(hwb, dis, offs, ssrc, scoef, bs, buf1);
    // layer 2: in = h1 + h0
    gemm_kernel<<<gemm_grid, 256, 0, stream>>>(buf1, buf0, Ws + H * H, hwb);
    agg_kernel<<<agg_grid, 256, 0, stream>>>(hwb, dis, offs, ssrc, scoef, bs + H, buf2);
    // layer 3: in = h2 + h1
    gemm_kernel<<<gemm_grid, 256, 0, stream>>>(buf2, buf1, Ws + 2 * H * H, hwb);
    agg_kernel<<<agg_grid, 256, 0, stream>>>(hwb, dis, offs, ssrc, scoef, bs + 2 * H, buf0);

    pool_kernel<<<NG, 128, 0, stream>>>(buf0, batch, linW, linb, (float*)d_out);
}

// Round 2
// 1126.804 us; speedup vs baseline: 1.0843x; 1.0843x over previous
//
#include <hip/hip_runtime.h>

#define NN 100000
#define NE 1600000
#define H  128
#define NG 512
#define NC 10
#define SCAN_B 98   // ceil(NN/1024)

typedef _Float16 f16;
typedef __attribute__((ext_vector_type(8))) _Float16 f16x8;
typedef __attribute__((ext_vector_type(4))) _Float16 f16x4;
typedef __attribute__((ext_vector_type(4))) float    f32x4;

// ---------------------------------------------------------------- utilities
__device__ __forceinline__ int lower_bound_i(const int* __restrict__ a, int n, int val) {
    int lo = 0, hi = n;
    while (lo < hi) {
        int mid = (lo + hi) >> 1;
        if (a[mid] < val) lo = mid + 1; else hi = mid;
    }
    return lo;
}

// ---------------------------------------------------------------- degree histogram
__global__ __launch_bounds__(256) void deg_kernel(const int* __restrict__ dst,
                                                  int* __restrict__ deg) {
    int e = blockIdx.x * 256 + threadIdx.x;
    if (e < NE) atomicAdd(&deg[dst[e]], 1);
}

// ---------------------------------------------------------------- parallel scan (3 stages)
__global__ __launch_bounds__(256) void scan1_kernel(const int* __restrict__ deg,
                                                    int* __restrict__ psum) {
    int b = blockIdx.x, t = threadIdx.x;
    int i4 = b * 1024 + t * 4;
    int s = 0;
    if (i4 + 3 < NN) {
        int4 v = *(const int4*)&deg[i4];
        s = v.x + v.y + v.z + v.w;
    } else {
        for (int k = 0; k < 4; ++k) if (i4 + k < NN) s += deg[i4 + k];
    }
    #pragma unroll
    for (int d = 32; d; d >>= 1) s += __shfl_down(s, d, 64);
    __shared__ int ws[4];
    if ((t & 63) == 0) ws[t >> 6] = s;
    __syncthreads();
    if (t == 0) psum[b] = ws[0] + ws[1] + ws[2] + ws[3];
}

__global__ void scan2_kernel(const int* __restrict__ psum, int* __restrict__ poff,
                             int* __restrict__ offs) {
    if (threadIdx.x == 0) {
        int run = 0;
        for (int b = 0; b < SCAN_B; ++b) { poff[b] = run; run += psum[b]; }
        offs[NN] = run;   // == NE
    }
}

__global__ __launch_bounds__(256) void scan3_kernel(const int* __restrict__ deg,
                                                    const int* __restrict__ poff,
                                                    int* __restrict__ offs,
                                                    int* __restrict__ cursor,
                                                    float* __restrict__ dis) {
    int b = blockIdx.x, t = threadIdx.x;
    int lane = t & 63, wid = t >> 6;
    int i4 = b * 1024 + t * 4;
    int v[4]; int s = 0;
    #pragma unroll
    for (int k = 0; k < 4; ++k) { int i = i4 + k; v[k] = (i < NN) ? deg[i] : 0; s += v[k]; }
    int incl = s;
    #pragma unroll
    for (int d = 1; d < 64; d <<= 1) { int u = __shfl_up(incl, d, 64); if (lane >= d) incl += u; }
    __shared__ int ws[4];
    if (lane == 63) ws[wid] = incl;
    __syncthreads();
    int wbase = 0;
    for (int w = 0; w < wid; ++w) wbase += ws[w];
    int base = poff[b] + wbase + incl - s;
    #pragma unroll
    for (int k = 0; k < 4; ++k) {
        int i = i4 + k;
        if (i < NN) {
            offs[i] = base; cursor[i] = base;
            dis[i] = rsqrtf((float)v[k] + 1.0f);
        }
        base += v[k];
    }
}

// bucket edges by dst; pack (src, coef) into int2 per edge
__global__ __launch_bounds__(256) void scatter_kernel(const int* __restrict__ src,
                                                      const int* __restrict__ dst,
                                                      const float* __restrict__ dis,
                                                      int* __restrict__ cursor,
                                                      int2* __restrict__ edata) {
    int e = blockIdx.x * 256 + threadIdx.x;
    if (e < NE) {
        int s = src[e], d = dst[e];
        int pos = atomicAdd(&cursor[d], 1);
        float c = dis[s] * dis[d];
        edata[pos] = make_int2(s, __float_as_int(c));
    }
}

// ---------------------------------------------------------------- GEMM: hw = fp16((in0 [+ in1]) @ W)
// 128x128 tile, K-chunks of 32, 8x8 micro-tile. A staged transposed [k][row] stride 132.
__global__ __launch_bounds__(256) void gemm_kernel(const float* __restrict__ in0,
                                                   const float* __restrict__ in1,
                                                   const float* __restrict__ W,
                                                   f16* __restrict__ hw) {
    __shared__ float sInT[32 * 132];   // [k_local][row], stride 132: b128-aligned, conflict-free
    __shared__ float sW[32 * H];       // [k_local][col]
    int t  = threadIdx.x;
    int tx = t & 15, ty = t >> 4;      // cols: tx*4 and tx*4+64 ; rows: ty*8..+7
    int row0 = blockIdx.x * 128;
    float acc[8][8];
    #pragma unroll
    for (int r = 0; r < 8; ++r)
        #pragma unroll
        for (int c = 0; c < 8; ++c) acc[r][c] = 0.f;

    for (int k0 = 0; k0 < H; k0 += 32) {
        __syncthreads();
        // stage A transposed
        #pragma unroll
        for (int i = 0; i < 4; ++i) {
            int f   = t + i * 256;          // 0..1023
            int row = f >> 3;               // 0..127
            int c4  = (f & 7) * 4;          // 0..28
            int grow = row0 + row;
            f32x4 v = {0.f, 0.f, 0.f, 0.f};
            if (grow < NN) {
                v = *(const f32x4*)&in0[(size_t)grow * H + k0 + c4];
                if (in1) {
                    f32x4 u = *(const f32x4*)&in1[(size_t)grow * H + k0 + c4];
                    v = v + u;
                }
            }
            sInT[(c4 + 0) * 132 + row] = v.x;
            sInT[(c4 + 1) * 132 + row] = v.y;
            sInT[(c4 + 2) * 132 + row] = v.z;
            sInT[(c4 + 3) * 132 + row] = v.w;
        }
        // stage W chunk 32x128
        #pragma unroll
        for (int i = 0; i < 4; ++i) {
            int g   = t + i * 256;
            int row = g >> 5;
            int c4  = (g & 31) * 4;
            *(f32x4*)&sW[row * H + c4] = *(const f32x4*)&W[(size_t)(k0 + row) * H + c4];
        }
        __syncthreads();
        #pragma unroll
        for (int kk = 0; kk < 32; ++kk) {
            f32x4 a0 = *(const f32x4*)&sInT[kk * 132 + ty * 8];
            f32x4 a1 = *(const f32x4*)&sInT[kk * 132 + ty * 8 + 4];
            f32x4 w0 = *(const f32x4*)&sW[kk * H + tx * 4];
            f32x4 w1 = *(const f32x4*)&sW[kk * H + tx * 4 + 64];
            float a[8] = {a0.x, a0.y, a0.z, a0.w, a1.x, a1.y, a1.z, a1.w};
            float w[8] = {w0.x, w0.y, w0.z, w0.w, w1.x, w1.y, w1.z, w1.w};
            #pragma unroll
            for (int r = 0; r < 8; ++r)
                #pragma unroll
                for (int c = 0; c < 8; ++c)
                    acc[r][c] += a[r] * w[c];
        }
    }
    #pragma unroll
    for (int r = 0; r < 8; ++r) {
        int grow = row0 + ty * 8 + r;
        if (grow < NN) {
            f16x4 o0, o1;
            #pragma unroll
            for (int c = 0; c < 4; ++c) { o0[c] = (f16)acc[r][c]; o1[c] = (f16)acc[r][c + 4]; }
            *(f16x4*)&hw[(size_t)grow * H + tx * 4]      = o0;
            *(f16x4*)&hw[(size_t)grow * H + tx * 4 + 64] = o1;
        }
    }
}

// ---------------------------------------------------------------- aggregation
// one wave per node; lane quarter q=lane>>4 owns edge slot, (lane&15)*8 = feature base (fp16x8 = 16B)
template <int FINAL>
__global__ __launch_bounds__(256) void agg_kernel_t(const f16* __restrict__ hw,
                                                    const float* __restrict__ dis,
                                                    const int* __restrict__ offs,
                                                    const int2* __restrict__ edata,
                                                    const float* __restrict__ bias,
                                                    float* __restrict__ outh,
                                                    const int* __restrict__ batch,
                                                    float* __restrict__ sums) {
    int wid  = threadIdx.x >> 6;
    int lane = threadIdx.x & 63;
    int node = blockIdx.x * 4 + wid;
    if (node >= NN) return;
    int q  = lane >> 4;
    int j8 = (lane & 15) * 8;
    int beg = offs[node], end = offs[node + 1];
    int nk = end - beg;
    float acc[8];
    #pragma unroll
    for (int u = 0; u < 8; ++u) acc[u] = 0.f;

    for (int k0 = 0; k0 < nk; k0 += 4) {
        int kk = k0 + q;
        int s = 0; float c = 0.f;
        if (kk < nk) {
            int2 e = edata[beg + kk];
            s = e.x; c = __int_as_float(e.y);
        }
        f16x8 v = *(const f16x8*)&hw[(size_t)s * H + j8];
        #pragma unroll
        for (int u = 0; u < 8; ++u) acc[u] += c * (float)v[u];
    }
    // self-loop term (count once: quarter 0 only)
    float dv = dis[node];
    f16x8 hv = *(const f16x8*)&hw[(size_t)node * H + j8];
    if (q == 0) {
        float sc = dv * dv;
        #pragma unroll
        for (int u = 0; u < 8; ++u) acc[u] += sc * (float)hv[u];
    }
    // reduce across quarters
    #pragma unroll
    for (int u = 0; u < 8; ++u) {
        acc[u] += __shfl_xor(acc[u], 16, 64);
        acc[u] += __shfl_xor(acc[u], 32, 64);
    }
    // bias + relu
    #pragma unroll
    for (int u = 0; u < 8; ++u) acc[u] = fmaxf(acc[u] + bias[j8 + u], 0.f);

    if (q == 0) {
        if (FINAL) {
            int g = batch[node];
            #pragma unroll
            for (int u = 0; u < 8; ++u) atomicAdd(&sums[g * H + j8 + u], acc[u]);
        } else {
            f32x4 o0 = {acc[0], acc[1], acc[2], acc[3]};
            f32x4 o1 = {acc[4], acc[5], acc[6], acc[7]};
            *(f32x4*)&outh[(size_t)node * H + j8]     = o0;
            *(f32x4*)&outh[(size_t)node * H + j8 + 4] = o1;
        }
    }
}

// ---------------------------------------------------------------- head: pooled/cnt @ linW + linb
__global__ __launch_bounds__(128) void head_kernel(const float* __restrict__ sums,
                                                   const int* __restrict__ batch,
                                                   const float* __restrict__ linW,
                                                   const float* __restrict__ linb,
                                                   float* __restrict__ out) {
    __shared__ float pld[H];
    int g = blockIdx.x;
    int t = threadIdx.x;
    int lo = lower_bound_i(batch, NN, g);
    int hi = lower_bound_i(batch, NN, g + 1);
    float cnt = (float)(hi - lo);
    pld[t] = sums[g * H + t] / fmaxf(cnt, 1.0f);
    __syncthreads();
    if (t < NC) {
        float acc = linb[t];
        #pragma unroll 4
        for (int j = 0; j < H; ++j) acc += pld[j] * linW[j * NC + t];
        out[g * NC + t] = acc;
    }
}

// ---------------------------------------------------------------- launch
extern "C" void kernel_launch(void* const* d_in, const int* in_sizes, int n_in,
                              void* d_out, int out_size, void* d_ws, size_t ws_size,
                              hipStream_t stream) {
    const float* x     = (const float*)d_in[0];
    const int*   ei    = (const int*)d_in[1];   // [2][NE] (harness converts int64->int32)
    const int*   batch = (const int*)d_in[2];
    const float* W0    = (const float*)d_in[3];
    const float* b0    = (const float*)d_in[4];
    const float* Ws    = (const float*)d_in[5]; // [3][H][H]
    const float* bs    = (const float*)d_in[6]; // [3][H]
    const float* linW  = (const float*)d_in[7];
    const float* linb  = (const float*)d_in[8];
    const int* src = ei;
    const int* dst = ei + NE;

    char* p = (char*)d_ws;
    auto alloc = [&](size_t bytes) -> void* {
        void* r = (void*)p;
        p += (bytes + 255) & ~(size_t)255;
        return r;
    };
    float* buf0   = (float*)alloc((size_t)NN * H * 4);
    float* buf1   = (float*)alloc((size_t)NN * H * 4);
    float* buf2   = (float*)alloc((size_t)NN * H * 4);
    f16*   hwb    = (f16*)alloc((size_t)NN * H * 2);
    float* dis    = (float*)alloc((size_t)NN * 4);
    int*   deg    = (int*)alloc((size_t)NN * 4);
    int*   offs   = (int*)alloc((size_t)(NN + 1) * 4);
    int*   cursor = (int*)alloc((size_t)NN * 4);
    int2*  edata  = (int2*)alloc((size_t)NE * 8);
    int*   psum   = (int*)alloc((size_t)SCAN_B * 4);
    int*   poff   = (int*)alloc((size_t)SCAN_B * 4);
    float* sums   = (float*)alloc((size_t)NG * H * 4);

    hipMemsetAsync(deg, 0, (size_t)NN * 4, stream);
    hipMemsetAsync(sums, 0, (size_t)NG * H * 4, stream);

    deg_kernel<<<(NE + 255) / 256, 256, 0, stream>>>(dst, deg);
    scan1_kernel<<<SCAN_B, 256, 0, stream>>>(deg, psum);
    scan2_kernel<<<1, 64, 0, stream>>>(psum, poff, offs);
    scan3_kernel<<<SCAN_B, 256, 0, stream>>>(deg, poff, offs, cursor, dis);
    scatter_kernel<<<(NE + 255) / 256, 256, 0, stream>>>(src, dst, dis, cursor, edata);

    int gemm_grid = (NN + 127) / 128;
    int agg_grid  = (NN + 3) / 4;

    // layer 0
    gemm_kernel<<<gemm_grid, 256, 0, stream>>>(x, nullptr, W0, hwb);
    agg_kernel_t<0><<<agg_grid, 256, 0, stream>>>(hwb, dis, offs, edata, b0, buf0, nullptr, nullptr);
    // layer 1 (input h0)
    gemm_kernel<<<gemm_grid, 256, 0, stream>>>(buf0, nullptr, Ws, hwb);
    agg_kernel_t<0><<<agg_grid, 256, 0, stream>>>(hwb, dis, offs, edata, bs, buf1, nullptr, nullptr);
    // layer 2 (input h1 + h0)
    gemm_kernel<<<gemm_grid, 256, 0, stream>>>(buf1, buf0, Ws + H * H, hwb);
    agg_kernel_t<0><<<agg_grid, 256, 0, stream>>>(hwb, dis, offs, edata, bs + H, buf2, nullptr, nullptr);
    // layer 3 (input h2 + h1) -> pooled sums directly
    gemm_kernel<<<gemm_grid, 256, 0, stream>>>(buf2, buf1, Ws + 2 * H * H, hwb);
    agg_kernel_t<1><<<agg_grid, 256, 0, stream>>>(hwb, dis, offs, edata, bs + 2 * H, nullptr, batch, sums);

    head_kernel<<<NG, 128, 0, stream>>>(sums, batch, linW, linb, (float*)d_out);
}

// Round 3
// 726.612 us; speedup vs baseline: 1.6815x; 1.5508x over previous
//
#include <hip/hip_runtime.h>

#define NN 100000
#define NE 1600000
#define H  128
#define NG 512
#define NC 10
#define SCAN_B 98   // ceil(NN/1024)

typedef _Float16 f16;
typedef __attribute__((ext_vector_type(8))) _Float16 f16x8;
typedef __attribute__((ext_vector_type(4))) _Float16 f16x4;
typedef __attribute__((ext_vector_type(4))) float    f32x4;

// ---------------------------------------------------------------- utilities
__device__ __forceinline__ int lower_bound_i(const int* __restrict__ a, int n, int val) {
    int lo = 0, hi = n;
    while (lo < hi) {
        int mid = (lo + hi) >> 1;
        if (a[mid] < val) lo = mid + 1; else hi = mid;
    }
    return lo;
}

// ---------------------------------------------------------------- degree histogram
__global__ __launch_bounds__(256) void deg_kernel(const int* __restrict__ dst,
                                                  int* __restrict__ deg) {
    int e = blockIdx.x * 256 + threadIdx.x;
    if (e < NE) atomicAdd(&deg[dst[e]], 1);
}

// ---------------------------------------------------------------- parallel scan (3 stages)
__global__ __launch_bounds__(256) void scan1_kernel(const int* __restrict__ deg,
                                                    int* __restrict__ psum) {
    int b = blockIdx.x, t = threadIdx.x;
    int i4 = b * 1024 + t * 4;
    int s = 0;
    if (i4 + 3 < NN) {
        int4 v = *(const int4*)&deg[i4];
        s = v.x + v.y + v.z + v.w;
    } else {
        for (int k = 0; k < 4; ++k) if (i4 + k < NN) s += deg[i4 + k];
    }
    #pragma unroll
    for (int d = 32; d; d >>= 1) s += __shfl_down(s, d, 64);
    __shared__ int ws[4];
    if ((t & 63) == 0) ws[t >> 6] = s;
    __syncthreads();
    if (t == 0) psum[b] = ws[0] + ws[1] + ws[2] + ws[3];
}

__global__ void scan2_kernel(const int* __restrict__ psum, int* __restrict__ poff,
                             int* __restrict__ offs) {
    if (threadIdx.x == 0) {
        int run = 0;
        for (int b = 0; b < SCAN_B; ++b) { poff[b] = run; run += psum[b]; }
        offs[NN] = run;   // == NE
    }
}

__global__ __launch_bounds__(256) void scan3_kernel(const int* __restrict__ deg,
                                                    const int* __restrict__ poff,
                                                    int* __restrict__ offs,
                                                    int* __restrict__ cursor,
                                                    float* __restrict__ dis) {
    int b = blockIdx.x, t = threadIdx.x;
    int lane = t & 63, wid = t >> 6;
    int i4 = b * 1024 + t * 4;
    int v[4]; int s = 0;
    #pragma unroll
    for (int k = 0; k < 4; ++k) { int i = i4 + k; v[k] = (i < NN) ? deg[i] : 0; s += v[k]; }
    int incl = s;
    #pragma unroll
    for (int d = 1; d < 64; d <<= 1) { int u = __shfl_up(incl, d, 64); if (lane >= d) incl += u; }
    __shared__ int ws[4];
    if (lane == 63) ws[wid] = incl;
    __syncthreads();
    int wbase = 0;
    for (int w = 0; w < wid; ++w) wbase += ws[w];
    int base = poff[b] + wbase + incl - s;
    #pragma unroll
    for (int k = 0; k < 4; ++k) {
        int i = i4 + k;
        if (i < NN) {
            offs[i] = base; cursor[i] = base;
            dis[i] = rsqrtf((float)v[k] + 1.0f);
        }
        base += v[k];
    }
}

// bucket edges by dst; pack (src, coef) into int2 per edge
__global__ __launch_bounds__(256) void scatter_kernel(const int* __restrict__ src,
                                                      const int* __restrict__ dst,
                                                      const float* __restrict__ dis,
                                                      int* __restrict__ cursor,
                                                      int2* __restrict__ edata) {
    int e = blockIdx.x * 256 + threadIdx.x;
    if (e < NE) {
        int s = src[e], d = dst[e];
        int pos = atomicAdd(&cursor[d], 1);
        float c = dis[s] * dis[d];
        edata[pos] = make_int2(s, __float_as_int(c));
    }
}

// ---------------------------------------------------------------- GEMM: hw = fp16((in0 [+ in1]) @ W)
// 128x128 tile, K-chunks of 32, 8x8 micro-tile. A staged transposed [k][row] stride 132.
__global__ __launch_bounds__(256) void gemm_kernel(const float* __restrict__ in0,
                                                   const float* __restrict__ in1,
                                                   const float* __restrict__ W,
                                                   f16* __restrict__ hw) {
    __shared__ float sInT[32 * 132];   // [k_local][row], stride 132: b128-aligned, conflict-free
    __shared__ float sW[32 * H];       // [k_local][col]
    int t  = threadIdx.x;
    int tx = t & 15, ty = t >> 4;      // cols: tx*4 and tx*4+64 ; rows: ty*8..+7
    int row0 = blockIdx.x * 128;
    float acc[8][8];
    #pragma unroll
    for (int r = 0; r < 8; ++r)
        #pragma unroll
        for (int c = 0; c < 8; ++c) acc[r][c] = 0.f;

    for (int k0 = 0; k0 < H; k0 += 32) {
        __syncthreads();
        // stage A transposed
        #pragma unroll
        for (int i = 0; i < 4; ++i) {
            int f   = t + i * 256;          // 0..1023
            int row = f >> 3;               // 0..127
            int c4  = (f & 7) * 4;          // 0..28
            int grow = row0 + row;
            f32x4 v = {0.f, 0.f, 0.f, 0.f};
            if (grow < NN) {
                v = *(const f32x4*)&in0[(size_t)grow * H + k0 + c4];
                if (in1) {
                    f32x4 u = *(const f32x4*)&in1[(size_t)grow * H + k0 + c4];
                    v = v + u;
                }
            }
            sInT[(c4 + 0) * 132 + row] = v.x;
            sInT[(c4 + 1) * 132 + row] = v.y;
            sInT[(c4 + 2) * 132 + row] = v.z;
            sInT[(c4 + 3) * 132 + row] = v.w;
        }
        // stage W chunk 32x128
        #pragma unroll
        for (int i = 0; i < 4; ++i) {
            int g   = t + i * 256;
            int row = g >> 5;
            int c4  = (g & 31) * 4;
            *(f32x4*)&sW[row * H + c4] = *(const f32x4*)&W[(size_t)(k0 + row) * H + c4];
        }
        __syncthreads();
        #pragma unroll
        for (int kk = 0; kk < 32; ++kk) {
            f32x4 a0 = *(const f32x4*)&sInT[kk * 132 + ty * 8];
            f32x4 a1 = *(const f32x4*)&sInT[kk * 132 + ty * 8 + 4];
            f32x4 w0 = *(const f32x4*)&sW[kk * H + tx * 4];
            f32x4 w1 = *(const f32x4*)&sW[kk * H + tx * 4 + 64];
            float a[8] = {a0.x, a0.y, a0.z, a0.w, a1.x, a1.y, a1.z, a1.w};
            float w[8] = {w0.x, w0.y, w0.z, w0.w, w1.x, w1.y, w1.z, w1.w};
            #pragma unroll
            for (int r = 0; r < 8; ++r)
                #pragma unroll
                for (int c = 0; c < 8; ++c)
                    acc[r][c] += a[r] * w[c];
        }
    }
    #pragma unroll
    for (int r = 0; r < 8; ++r) {
        int grow = row0 + ty * 8 + r;
        if (grow < NN) {
            f16x4 o0, o1;
            #pragma unroll
            for (int c = 0; c < 4; ++c) { o0[c] = (f16)acc[r][c]; o1[c] = (f16)acc[r][c + 4]; }
            *(f16x4*)&hw[(size_t)grow * H + tx * 4]      = o0;
            *(f16x4*)&hw[(size_t)grow * H + tx * 4 + 64] = o1;
        }
    }
}

// ---------------------------------------------------------------- aggregation
// one wave per node; lane quarter q=lane>>4 owns edge slot, (lane&15)*8 = feature base (fp16x8 = 16B)
__global__ __launch_bounds__(256) void agg_kernel(const f16* __restrict__ hw,
                                                  const float* __restrict__ dis,
                                                  const int* __restrict__ offs,
                                                  const int2* __restrict__ edata,
                                                  const float* __restrict__ bias,
                                                  float* __restrict__ outh) {
    int wid  = threadIdx.x >> 6;
    int lane = threadIdx.x & 63;
    int node = blockIdx.x * 4 + wid;
    if (node >= NN) return;
    int q  = lane >> 4;
    int j8 = (lane & 15) * 8;
    int beg = offs[node], end = offs[node + 1];
    int nk = end - beg;
    float acc[8];
    #pragma unroll
    for (int u = 0; u < 8; ++u) acc[u] = 0.f;

    for (int k0 = 0; k0 < nk; k0 += 4) {
        int kk = k0 + q;
        int s = 0; float c = 0.f;
        if (kk < nk) {
            int2 e = edata[beg + kk];
            s = e.x; c = __int_as_float(e.y);
        }
        f16x8 v = *(const f16x8*)&hw[(size_t)s * H + j8];
        #pragma unroll
        for (int u = 0; u < 8; ++u) acc[u] += c * (float)v[u];
    }
    // self-loop term (count once: quarter 0 only)
    float dv = dis[node];
    f16x8 hv = *(const f16x8*)&hw[(size_t)node * H + j8];
    if (q == 0) {
        float sc = dv * dv;
        #pragma unroll
        for (int u = 0; u < 8; ++u) acc[u] += sc * (float)hv[u];
    }
    // reduce across quarters
    #pragma unroll
    for (int u = 0; u < 8; ++u) {
        acc[u] += __shfl_xor(acc[u], 16, 64);
        acc[u] += __shfl_xor(acc[u], 32, 64);
    }
    // bias + relu + store (quarter 0)
    #pragma unroll
    for (int u = 0; u < 8; ++u) acc[u] = fmaxf(acc[u] + bias[j8 + u], 0.f);

    if (q == 0) {
        f32x4 o0 = {acc[0], acc[1], acc[2], acc[3]};
        f32x4 o1 = {acc[4], acc[5], acc[6], acc[7]};
        *(f32x4*)&outh[(size_t)node * H + j8]     = o0;
        *(f32x4*)&outh[(size_t)node * H + j8 + 4] = o1;
    }
}

// ---------------------------------------------------------------- mean-pool + linear head
__global__ __launch_bounds__(128) void pool_kernel(const float* __restrict__ h,
                                                   const int* __restrict__ batch,
                                                   const float* __restrict__ linW,
                                                   const float* __restrict__ linb,
                                                   float* __restrict__ out) {
    __shared__ float pld[H];
    int g = blockIdx.x;
    int t = threadIdx.x;
    int lo = lower_bound_i(batch, NN, g);
    int hi = lower_bound_i(batch, NN, g + 1);
    float sum = 0.f;
    #pragma unroll 4
    for (int n = lo; n < hi; ++n) sum += h[(size_t)n * H + t];
    float cnt = (float)(hi - lo);
    pld[t] = sum / fmaxf(cnt, 1.0f);
    __syncthreads();
    if (t < NC) {
        float acc = linb[t];
        #pragma unroll 4
        for (int j = 0; j < H; ++j) acc += pld[j] * linW[j * NC + t];
        out[g * NC + t] = acc;
    }
}

// ---------------------------------------------------------------- launch
extern "C" void kernel_launch(void* const* d_in, const int* in_sizes, int n_in,
                              void* d_out, int out_size, void* d_ws, size_t ws_size,
                              hipStream_t stream) {
    const float* x     = (const float*)d_in[0];
    const int*   ei    = (const int*)d_in[1];   // [2][NE]
    const int*   batch = (const int*)d_in[2];
    const float* W0    = (const float*)d_in[3];
    const float* b0    = (const float*)d_in[4];
    const float* Ws    = (const float*)d_in[5]; // [3][H][H]
    const float* bs    = (const float*)d_in[6]; // [3][H]
    const float* linW  = (const float*)d_in[7];
    const float* linb  = (const float*)d_in[8];
    const int* src = ei;
    const int* dst = ei + NE;

    char* p = (char*)d_ws;
    auto alloc = [&](size_t bytes) -> void* {
        void* r = (void*)p;
        p += (bytes + 255) & ~(size_t)255;
        return r;
    };
    float* buf0   = (float*)alloc((size_t)NN * H * 4);
    float* buf1   = (float*)alloc((size_t)NN * H * 4);
    float* buf2   = (float*)alloc((size_t)NN * H * 4);
    f16*   hwb    = (f16*)alloc((size_t)NN * H * 2);
    float* dis    = (float*)alloc((size_t)NN * 4);
    int*   deg    = (int*)alloc((size_t)NN * 4);
    int*   offs   = (int*)alloc((size_t)(NN + 1) * 4);
    int*   cursor = (int*)alloc((size_t)NN * 4);
    int2*  edata  = (int2*)alloc((size_t)NE * 8);
    int*   psum   = (int*)alloc((size_t)SCAN_B * 4);
    int*   poff   = (int*)alloc((size_t)SCAN_B * 4);

    hipMemsetAsync(deg, 0, (size_t)NN * 4, stream);

    deg_kernel<<<(NE + 255) / 256, 256, 0, stream>>>(dst, deg);
    scan1_kernel<<<SCAN_B, 256, 0, stream>>>(deg, psum);
    scan2_kernel<<<1, 64, 0, stream>>>(psum, poff, offs);
    scan3_kernel<<<SCAN_B, 256, 0, stream>>>(deg, poff, offs, cursor, dis);
    scatter_kernel<<<(NE + 255) / 256, 256, 0, stream>>>(src, dst, dis, cursor, edata);

    int gemm_grid = (NN + 127) / 128;
    int agg_grid  = (NN + 3) / 4;

    // layer 0
    gemm_kernel<<<gemm_grid, 256, 0, stream>>>(x, nullptr, W0, hwb);
    agg_kernel<<<agg_grid, 256, 0, stream>>>(hwb, dis, offs, edata, b0, buf0);
    // layer 1 (input h0)
    gemm_kernel<<<gemm_grid, 256, 0, stream>>>(buf0, nullptr, Ws, hwb);
    agg_kernel<<<agg_grid, 256, 0, stream>>>(hwb, dis, offs, edata, bs, buf1);
    // layer 2 (input h1 + h0)
    gemm_kernel<<<gemm_grid, 256, 0, stream>>>(buf1, buf0, Ws + H * H, hwb);
    agg_kernel<<<agg_grid, 256, 0, stream>>>(hwb, dis, offs, edata, bs + H, buf2);
    // layer 3 (input h2 + h1)
    gemm_kernel<<<gemm_grid, 256, 0, stream>>>(buf2, buf1, Ws + 2 * H * H, hwb);
    agg_kernel<<<agg_grid, 256, 0, stream>>>(hwb, dis, offs, edata, bs + 2 * H, buf0);

    pool_kernel<<<NG, 128, 0, stream>>>(buf0, batch, linW, linb, (float*)d_out);
}

// Round 4
// 696.565 us; speedup vs baseline: 1.7540x; 1.0431x over previous
//
#include <hip/hip_runtime.h>

#define NN 100000
#define NE 1600000
#define H  128
#define NG 512
#define NC 10
#define SCAN_B 98     // ceil(NN/1024) ; also = number of dst buckets (dst>>10)
#define NBUCK  98
#define CHUNK  4096   // edges per pass-A block

typedef _Float16 f16;
typedef __attribute__((ext_vector_type(8))) _Float16 f16x8;
typedef __attribute__((ext_vector_type(4))) _Float16 f16x4;
typedef __attribute__((ext_vector_type(4))) float    f32x4;

// ---------------------------------------------------------------- utilities
__device__ __forceinline__ int lower_bound_i(const int* __restrict__ a, int n, int val) {
    int lo = 0, hi = n;
    while (lo < hi) {
        int mid = (lo + hi) >> 1;
        if (a[mid] < val) lo = mid + 1; else hi = mid;
    }
    return lo;
}

// ---------------------------------------------------------------- degree histogram
__global__ __launch_bounds__(256) void deg_kernel(const int* __restrict__ dst,
                                                  int* __restrict__ deg) {
    int e = blockIdx.x * 256 + threadIdx.x;
    if (e < NE) atomicAdd(&deg[dst[e]], 1);
}

// ---------------------------------------------------------------- parallel scan (3 stages)
__global__ __launch_bounds__(256) void scan1_kernel(const int* __restrict__ deg,
                                                    int* __restrict__ psum) {
    int b = blockIdx.x, t = threadIdx.x;
    int i4 = b * 1024 + t * 4;
    int s = 0;
    if (i4 + 3 < NN) {
        int4 v = *(const int4*)&deg[i4];
        s = v.x + v.y + v.z + v.w;
    } else {
        for (int k = 0; k < 4; ++k) if (i4 + k < NN) s += deg[i4 + k];
    }
    #pragma unroll
    for (int d = 32; d; d >>= 1) s += __shfl_down(s, d, 64);
    __shared__ int ws[4];
    if ((t & 63) == 0) ws[t >> 6] = s;
    __syncthreads();
    if (t == 0) psum[b] = ws[0] + ws[1] + ws[2] + ws[3];
}

// poff[b] = start offset of scan-block/bucket b; bcur = working cursor copy
__global__ void scan2_kernel(const int* __restrict__ psum, int* __restrict__ poff,
                             int* __restrict__ offs, int* __restrict__ bcur) {
    if (threadIdx.x == 0) {
        int run = 0;
        for (int b = 0; b < SCAN_B; ++b) { poff[b] = run; bcur[b] = run; run += psum[b]; }
        poff[SCAN_B] = run;   // == NE
        offs[NN] = run;
    }
}

__global__ __launch_bounds__(256) void scan3_kernel(const int* __restrict__ deg,
                                                    const int* __restrict__ poff,
                                                    int* __restrict__ offs,
                                                    float* __restrict__ dis) {
    int b = blockIdx.x, t = threadIdx.x;
    int lane = t & 63, wid = t >> 6;
    int i4 = b * 1024 + t * 4;
    int v[4]; int s = 0;
    #pragma unroll
    for (int k = 0; k < 4; ++k) { int i = i4 + k; v[k] = (i < NN) ? deg[i] : 0; s += v[k]; }
    int incl = s;
    #pragma unroll
    for (int d = 1; d < 64; d <<= 1) { int u = __shfl_up(incl, d, 64); if (lane >= d) incl += u; }
    __shared__ int ws[4];
    if (lane == 63) ws[wid] = incl;
    __syncthreads();
    int wbase = 0;
    for (int w = 0; w < wid; ++w) wbase += ws[w];
    int base = poff[b] + wbase + incl - s;
    #pragma unroll
    for (int k = 0; k < 4; ++k) {
        int i = i4 + k;
        if (i < NN) {
            offs[i] = base;
            dis[i] = rsqrtf((float)v[k] + 1.0f);
        }
        base += v[k];
    }
}

// ---------------------------------------------------------------- pass A: bin edges by coarse bucket (dst>>10)
// payload: x = src | (dstloc<<17), y = fp32 coef bits
__global__ __launch_bounds__(256) void binA_kernel(const int* __restrict__ src,
                                                   const int* __restrict__ dst,
                                                   const float* __restrict__ dis,
                                                   int* __restrict__ bcur,
                                                   int2* __restrict__ binned) {
    __shared__ int  hist[NBUCK];
    __shared__ int  lbase[NBUCK];
    __shared__ int  gbase[NBUCK];
    __shared__ int  cur[NBUCK];
    __shared__ int2 stage[CHUNK];
    __shared__ int  destp[CHUNK];
    int t  = threadIdx.x;
    int e0 = blockIdx.x * CHUNK;
    int cnt = NE - e0; if (cnt > CHUNK) cnt = CHUNK;

    if (t < NBUCK) hist[t] = 0;
    __syncthreads();

    int s_[16], d_[16];
    #pragma unroll
    for (int i = 0; i < 16; ++i) {
        int e = e0 + i * 256 + t;
        if (e < NE) {
            s_[i] = src[e]; d_[i] = dst[e];
            atomicAdd(&hist[d_[i] >> 10], 1);
        } else { s_[i] = -1; d_[i] = 0; }
    }
    __syncthreads();

    if (t < NBUCK) {
        int lb = 0;
        for (int i = 0; i < t; ++i) lb += hist[i];
        lbase[t] = lb;
        cur[t]   = lb;
        gbase[t] = atomicAdd(&bcur[t], hist[t]);
    }
    __syncthreads();

    #pragma unroll
    for (int i = 0; i < 16; ++i) {
        if (s_[i] >= 0) {
            int s = s_[i], d = d_[i];
            int b = d >> 10;
            int r = atomicAdd(&cur[b], 1);
            float c = dis[s] * dis[d];
            stage[r] = make_int2(s | ((d & 1023) << 17), __float_as_int(c));
            destp[r] = gbase[b] + (r - lbase[b]);
        }
    }
    __syncthreads();

    #pragma unroll
    for (int i = 0; i < 16; ++i) {
        int idx = i * 256 + t;
        if (idx < cnt) binned[destp[idx]] = stage[idx];
    }
}

// ---------------------------------------------------------------- pass B: exact CSR placement within each bucket
__global__ __launch_bounds__(256) void binB_kernel(const int2* __restrict__ binned,
                                                   const int* __restrict__ poff,
                                                   const int* __restrict__ offs,
                                                   int2* __restrict__ edata) {
    __shared__ int cnt1k[1024];
    int b = blockIdx.x, t = threadIdx.x;
    #pragma unroll
    for (int i = 0; i < 4; ++i) cnt1k[t + i * 256] = 0;
    __syncthreads();
    int lo = poff[b], hi = poff[b + 1];
    for (int e = lo + t; e < hi; e += 256) {
        int2 p = binned[e];
        int dloc = (p.x >> 17) & 1023;
        int r = atomicAdd(&cnt1k[dloc], 1);
        int d = (b << 10) + dloc;
        edata[offs[d] + r] = p;
    }
}

// ---------------------------------------------------------------- GEMM: hw = fp16((in0 [+ in1]) @ W)
__global__ __launch_bounds__(256) void gemm_kernel(const float* __restrict__ in0,
                                                   const float* __restrict__ in1,
                                                   const float* __restrict__ W,
                                                   f16* __restrict__ hw) {
    __shared__ float sInT[32 * 132];
    __shared__ float sW[32 * H];
    int t  = threadIdx.x;
    int tx = t & 15, ty = t >> 4;
    int row0 = blockIdx.x * 128;
    float acc[8][8];
    #pragma unroll
    for (int r = 0; r < 8; ++r)
        #pragma unroll
        for (int c = 0; c < 8; ++c) acc[r][c] = 0.f;

    for (int k0 = 0; k0 < H; k0 += 32) {
        __syncthreads();
        #pragma unroll
        for (int i = 0; i < 4; ++i) {
            int f   = t + i * 256;
            int row = f >> 3;
            int c4  = (f & 7) * 4;
            int grow = row0 + row;
            f32x4 v = {0.f, 0.f, 0.f, 0.f};
            if (grow < NN) {
                v = *(const f32x4*)&in0[(size_t)grow * H + k0 + c4];
                if (in1) {
                    f32x4 u = *(const f32x4*)&in1[(size_t)grow * H + k0 + c4];
                    v = v + u;
                }
            }
            sInT[(c4 + 0) * 132 + row] = v.x;
            sInT[(c4 + 1) * 132 + row] = v.y;
            sInT[(c4 + 2) * 132 + row] = v.z;
            sInT[(c4 + 3) * 132 + row] = v.w;
        }
        #pragma unroll
        for (int i = 0; i < 4; ++i) {
            int g   = t + i * 256;
            int row = g >> 5;
            int c4  = (g & 31) * 4;
            *(f32x4*)&sW[row * H + c4] = *(const f32x4*)&W[(size_t)(k0 + row) * H + c4];
        }
        __syncthreads();
        #pragma unroll
        for (int kk = 0; kk < 32; ++kk) {
            f32x4 a0 = *(const f32x4*)&sInT[kk * 132 + ty * 8];
            f32x4 a1 = *(const f32x4*)&sInT[kk * 132 + ty * 8 + 4];
            f32x4 w0 = *(const f32x4*)&sW[kk * H + tx * 4];
            f32x4 w1 = *(const f32x4*)&sW[kk * H + tx * 4 + 64];
            float a[8] = {a0.x, a0.y, a0.z, a0.w, a1.x, a1.y, a1.z, a1.w};
            float w[8] = {w0.x, w0.y, w0.z, w0.w, w1.x, w1.y, w1.z, w1.w};
            #pragma unroll
            for (int r = 0; r < 8; ++r)
                #pragma unroll
                for (int c = 0; c < 8; ++c)
                    acc[r][c] += a[r] * w[c];
        }
    }
    #pragma unroll
    for (int r = 0; r < 8; ++r) {
        int grow = row0 + ty * 8 + r;
        if (grow < NN) {
            f16x4 o0, o1;
            #pragma unroll
            for (int c = 0; c < 4; ++c) { o0[c] = (f16)acc[r][c]; o1[c] = (f16)acc[r][c + 4]; }
            *(f16x4*)&hw[(size_t)grow * H + tx * 4]      = o0;
            *(f16x4*)&hw[(size_t)grow * H + tx * 4 + 64] = o1;
        }
    }
}

// ---------------------------------------------------------------- aggregation
__global__ __launch_bounds__(256) void agg_kernel(const f16* __restrict__ hw,
                                                  const float* __restrict__ dis,
                                                  const int* __restrict__ offs,
                                                  const int2* __restrict__ edata,
                                                  const float* __restrict__ bias,
                                                  float* __restrict__ outh) {
    int wid  = threadIdx.x >> 6;
    int lane = threadIdx.x & 63;
    int node = blockIdx.x * 4 + wid;
    if (node >= NN) return;
    int q  = lane >> 4;
    int j8 = (lane & 15) * 8;
    int beg = offs[node], end = offs[node + 1];
    int nk = end - beg;
    float acc[8];
    #pragma unroll
    for (int u = 0; u < 8; ++u) acc[u] = 0.f;

    for (int k0 = 0; k0 < nk; k0 += 4) {
        int kk = k0 + q;
        int s = 0; float c = 0.f;
        if (kk < nk) {
            int2 e = edata[beg + kk];
            s = e.x & 0x1FFFF;
            c = __int_as_float(e.y);
        }
        f16x8 v = *(const f16x8*)&hw[(size_t)s * H + j8];
        #pragma unroll
        for (int u = 0; u < 8; ++u) acc[u] += c * (float)v[u];
    }
    float dv = dis[node];
    f16x8 hv = *(const f16x8*)&hw[(size_t)node * H + j8];
    if (q == 0) {
        float sc = dv * dv;
        #pragma unroll
        for (int u = 0; u < 8; ++u) acc[u] += sc * (float)hv[u];
    }
    #pragma unroll
    for (int u = 0; u < 8; ++u) {
        acc[u] += __shfl_xor(acc[u], 16, 64);
        acc[u] += __shfl_xor(acc[u], 32, 64);
    }
    #pragma unroll
    for (int u = 0; u < 8; ++u) acc[u] = fmaxf(acc[u] + bias[j8 + u], 0.f);

    if (q == 0) {
        f32x4 o0 = {acc[0], acc[1], acc[2], acc[3]};
        f32x4 o1 = {acc[4], acc[5], acc[6], acc[7]};
        *(f32x4*)&outh[(size_t)node * H + j8]     = o0;
        *(f32x4*)&outh[(size_t)node * H + j8 + 4] = o1;
    }
}

// ---------------------------------------------------------------- mean-pool + linear head
__global__ __launch_bounds__(128) void pool_kernel(const float* __restrict__ h,
                                                   const int* __restrict__ batch,
                                                   const float* __restrict__ linW,
                                                   const float* __restrict__ linb,
                                                   float* __restrict__ out) {
    __shared__ float pld[H];
    int g = blockIdx.x;
    int t = threadIdx.x;
    int lo = lower_bound_i(batch, NN, g);
    int hi = lower_bound_i(batch, NN, g + 1);
    float sum = 0.f;
    #pragma unroll 4
    for (int n = lo; n < hi; ++n) sum += h[(size_t)n * H + t];
    float cnt = (float)(hi - lo);
    pld[t] = sum / fmaxf(cnt, 1.0f);
    __syncthreads();
    if (t < NC) {
        float acc = linb[t];
        #pragma unroll 4
        for (int j = 0; j < H; ++j) acc += pld[j] * linW[j * NC + t];
        out[g * NC + t] = acc;
    }
}

// ---------------------------------------------------------------- launch
extern "C" void kernel_launch(void* const* d_in, const int* in_sizes, int n_in,
                              void* d_out, int out_size, void* d_ws, size_t ws_size,
                              hipStream_t stream) {
    const float* x     = (const float*)d_in[0];
    const int*   ei    = (const int*)d_in[1];
    const int*   batch = (const int*)d_in[2];
    const float* W0    = (const float*)d_in[3];
    const float* b0    = (const float*)d_in[4];
    const float* Ws    = (const float*)d_in[5];
    const float* bs    = (const float*)d_in[6];
    const float* linW  = (const float*)d_in[7];
    const float* linb  = (const float*)d_in[8];
    const int* src = ei;
    const int* dst = ei + NE;

    char* p = (char*)d_ws;
    auto alloc = [&](size_t bytes) -> void* {
        void* r = (void*)p;
        p += (bytes + 255) & ~(size_t)255;
        return r;
    };
    float* buf0   = (float*)alloc((size_t)NN * H * 4);
    float* buf1   = (float*)alloc((size_t)NN * H * 4);
    float* buf2   = (float*)alloc((size_t)NN * H * 4);
    f16*   hwb    = (f16*)alloc((size_t)NN * H * 2);
    float* dis    = (float*)alloc((size_t)NN * 4);
    int*   deg    = (int*)alloc((size_t)NN * 4);
    int*   offs   = (int*)alloc((size_t)(NN + 1) * 4);
    int2*  binned = (int2*)alloc((size_t)NE * 8);
    int2*  edata  = (int2*)alloc((size_t)NE * 8);
    int*   psum   = (int*)alloc((size_t)SCAN_B * 4);
    int*   poff   = (int*)alloc((size_t)(SCAN_B + 1) * 4);
    int*   bcur   = (int*)alloc((size_t)NBUCK * 4);

    hipMemsetAsync(deg, 0, (size_t)NN * 4, stream);

    deg_kernel<<<(NE + 255) / 256, 256, 0, stream>>>(dst, deg);
    scan1_kernel<<<SCAN_B, 256, 0, stream>>>(deg, psum);
    scan2_kernel<<<1, 64, 0, stream>>>(psum, poff, offs, bcur);
    scan3_kernel<<<SCAN_B, 256, 0, stream>>>(deg, poff, offs, dis);
    binA_kernel<<<(NE + CHUNK - 1) / CHUNK, 256, 0, stream>>>(src, dst, dis, bcur, binned);
    binB_kernel<<<NBUCK, 256, 0, stream>>>(binned, poff, offs, edata);

    int gemm_grid = (NN + 127) / 128;
    int agg_grid  = (NN + 3) / 4;

    gemm_kernel<<<gemm_grid, 256, 0, stream>>>(x, nullptr, W0, hwb);
    agg_kernel<<<agg_grid, 256, 0, stream>>>(hwb, dis, offs, edata, b0, buf0);
    gemm_kernel<<<gemm_grid, 256, 0, stream>>>(buf0, nullptr, Ws, hwb);
    agg_kernel<<<agg_grid, 256, 0, stream>>>(hwb, dis, offs, edata, bs, buf1);
    gemm_kernel<<<gemm_grid, 256, 0, stream>>>(buf1, buf0, Ws + H * H, hwb);
    agg_kernel<<<agg_grid, 256, 0, stream>>>(hwb, dis, offs, edata, bs + H, buf2);
    gemm_kernel<<<gemm_grid, 256, 0, stream>>>(buf2, buf1, Ws + 2 * H * H, hwb);
    agg_kernel<<<agg_grid, 256, 0, stream>>>(hwb, dis, offs, edata, bs + 2 * H, buf0);

    pool_kernel<<<NG, 128, 0, stream>>>(buf0, batch, linW, linb, (float*)d_out);
}

// Round 5
// 559.306 us; speedup vs baseline: 2.1844x; 1.2454x over previous
//
#include <hip/hip_runtime.h>

#define NN 100000
#define NE 1600000
#define H  128
#define NG 512
#define NC 10
#define SCAN_B 98     // ceil(NN/1024) ; also = number of dst buckets (dst>>10)
#define NBUCK  98
#define CHUNK  4096   // edges per pass-A block

typedef _Float16 f16;
typedef __attribute__((ext_vector_type(8))) _Float16 f16x8;
typedef __attribute__((ext_vector_type(4))) float    f32x4;

// ---------------------------------------------------------------- utilities
__device__ __forceinline__ int lower_bound_i(const int* __restrict__ a, int n, int val) {
    int lo = 0, hi = n;
    while (lo < hi) {
        int mid = (lo + hi) >> 1;
        if (a[mid] < val) lo = mid + 1; else hi = mid;
    }
    return lo;
}

// ---------------------------------------------------------------- degree histogram
__global__ __launch_bounds__(256) void deg_kernel(const int* __restrict__ dst,
                                                  int* __restrict__ deg) {
    int e = blockIdx.x * 256 + threadIdx.x;
    if (e < NE) atomicAdd(&deg[dst[e]], 1);
}

// ---------------------------------------------------------------- parallel scan (3 stages)
__global__ __launch_bounds__(256) void scan1_kernel(const int* __restrict__ deg,
                                                    int* __restrict__ psum) {
    int b = blockIdx.x, t = threadIdx.x;
    int i4 = b * 1024 + t * 4;
    int s = 0;
    if (i4 + 3 < NN) {
        int4 v = *(const int4*)&deg[i4];
        s = v.x + v.y + v.z + v.w;
    } else {
        for (int k = 0; k < 4; ++k) if (i4 + k < NN) s += deg[i4 + k];
    }
    #pragma unroll
    for (int d = 32; d; d >>= 1) s += __shfl_down(s, d, 64);
    __shared__ int ws[4];
    if ((t & 63) == 0) ws[t >> 6] = s;
    __syncthreads();
    if (t == 0) psum[b] = ws[0] + ws[1] + ws[2] + ws[3];
}

__global__ void scan2_kernel(const int* __restrict__ psum, int* __restrict__ poff,
                             int* __restrict__ offs, int* __restrict__ bcur) {
    if (threadIdx.x == 0) {
        int run = 0;
        for (int b = 0; b < SCAN_B; ++b) { poff[b] = run; bcur[b] = run; run += psum[b]; }
        poff[SCAN_B] = run;
        offs[NN] = run;
    }
}

__global__ __launch_bounds__(256) void scan3_kernel(const int* __restrict__ deg,
                                                    const int* __restrict__ poff,
                                                    int* __restrict__ offs,
                                                    float* __restrict__ dis) {
    int b = blockIdx.x, t = threadIdx.x;
    int lane = t & 63, wid = t >> 6;
    int i4 = b * 1024 + t * 4;
    int v[4]; int s = 0;
    #pragma unroll
    for (int k = 0; k < 4; ++k) { int i = i4 + k; v[k] = (i < NN) ? deg[i] : 0; s += v[k]; }
    int incl = s;
    #pragma unroll
    for (int d = 1; d < 64; d <<= 1) { int u = __shfl_up(incl, d, 64); if (lane >= d) incl += u; }
    __shared__ int ws[4];
    if (lane == 63) ws[wid] = incl;
    __syncthreads();
    int wbase = 0;
    for (int w = 0; w < wid; ++w) wbase += ws[w];
    int base = poff[b] + wbase + incl - s;
    #pragma unroll
    for (int k = 0; k < 4; ++k) {
        int i = i4 + k;
        if (i < NN) {
            offs[i] = base;
            dis[i] = rsqrtf((float)v[k] + 1.0f);
        }
        base += v[k];
    }
}

// ---------------------------------------------------------------- pass A: bin edges by coarse bucket (dst>>10)
__global__ __launch_bounds__(256) void binA_kernel(const int* __restrict__ src,
                                                   const int* __restrict__ dst,
                                                   const float* __restrict__ dis,
                                                   int* __restrict__ bcur,
                                                   int2* __restrict__ binned) {
    __shared__ int  hist[NBUCK];
    __shared__ int  lbase[NBUCK];
    __shared__ int  gbase[NBUCK];
    __shared__ int  cur[NBUCK];
    __shared__ int2 stage[CHUNK];
    __shared__ int  destp[CHUNK];
    int t  = threadIdx.x;
    int e0 = blockIdx.x * CHUNK;
    int cnt = NE - e0; if (cnt > CHUNK) cnt = CHUNK;

    if (t < NBUCK) hist[t] = 0;
    __syncthreads();

    int s_[16], d_[16];
    #pragma unroll
    for (int i = 0; i < 16; ++i) {
        int e = e0 + i * 256 + t;
        if (e < NE) {
            s_[i] = src[e]; d_[i] = dst[e];
            atomicAdd(&hist[d_[i] >> 10], 1);
        } else { s_[i] = -1; d_[i] = 0; }
    }
    __syncthreads();

    if (t < NBUCK) {
        int lb = 0;
        for (int i = 0; i < t; ++i) lb += hist[i];
        lbase[t] = lb;
        cur[t]   = lb;
        gbase[t] = atomicAdd(&bcur[t], hist[t]);
    }
    __syncthreads();

    #pragma unroll
    for (int i = 0; i < 16; ++i) {
        if (s_[i] >= 0) {
            int s = s_[i], d = d_[i];
            int b = d >> 10;
            int r = atomicAdd(&cur[b], 1);
            float c = dis[s] * dis[d];
            stage[r] = make_int2(s | ((d & 1023) << 17), __float_as_int(c));
            destp[r] = gbase[b] + (r - lbase[b]);
        }
    }
    __syncthreads();

    #pragma unroll
    for (int i = 0; i < 16; ++i) {
        int idx = i * 256 + t;
        if (idx < cnt) binned[destp[idx]] = stage[idx];
    }
}

// ---------------------------------------------------------------- pass B: exact CSR placement within each bucket
__global__ __launch_bounds__(256) void binB_kernel(const int2* __restrict__ binned,
                                                   const int* __restrict__ poff,
                                                   const int* __restrict__ offs,
                                                   int2* __restrict__ edata) {
    __shared__ int cnt1k[1024];
    int b = blockIdx.x, t = threadIdx.x;
    #pragma unroll
    for (int i = 0; i < 4; ++i) cnt1k[t + i * 256] = 0;
    __syncthreads();
    int lo = poff[b], hi = poff[b + 1];
    for (int e = lo + t; e < hi; e += 256) {
        int2 p = binned[e];
        int dloc = (p.x >> 17) & 1023;
        int r = atomicAdd(&cnt1k[dloc], 1);
        int d = (b << 10) + dloc;
        edata[offs[d] + r] = p;
    }
}

// ---------------------------------------------------------------- W split prep: Wt_hi/Wt_lo [4][128][128] fp16, transposed
__global__ __launch_bounds__(256) void wprep_kernel(const float* __restrict__ W0,
                                                    const float* __restrict__ Ws,
                                                    f16* __restrict__ wt_hi,
                                                    f16* __restrict__ wt_lo) {
    int idx = blockIdx.x * 256 + threadIdx.x;   // 4*16384 total
    int m = idx >> 14;
    int k = (idx >> 7) & 127;
    int n = idx & 127;
    const float* Wm = (m == 0) ? W0 : (Ws + (size_t)(m - 1) * H * H);
    float v = Wm[k * H + n];
    f16 hi = (f16)v;
    float lo = v - (float)hi;
    wt_hi[(size_t)m * H * H + n * H + k] = hi;
    wt_lo[(size_t)m * H * H + n * H + k] = (f16)lo;
}

// ---------------------------------------------------------------- MFMA GEMM: hw = fp16((in0 [+ in1]) @ (W_hi + W_lo))
// 256 rows/block, 512 threads (8 waves, 32 rows each). LDS 128 KB.
// frag layout (16x16x32): A/B lane l: dim=l&15, k=(l>>4)*8+j ; D: col=l&15, row=(l>>4)*4+reg
template <int FP32IN>
__global__ __launch_bounds__(512) void gemm_kernel(const void* __restrict__ in0,
                                                   const f16* __restrict__ in1,
                                                   const f16* __restrict__ wt_hi,
                                                   const f16* __restrict__ wt_lo,
                                                   f16* __restrict__ hw) {
    __shared__ f16x8 sA[256 * 16];      // 64 KB, chunk-swizzled (c ^ (row&7))
    __shared__ f16x8 sW[2][128 * 16];   // 64 KB
    int t = threadIdx.x;
    int row0 = blockIdx.x * 256;

    const f16x8* wh = (const f16x8*)wt_hi;
    const f16x8* wl = (const f16x8*)wt_lo;
    #pragma unroll
    for (int i = 0; i < 4; ++i) {
        int ch = i * 512 + t;           // 0..2047
        int n = ch >> 4, c = ch & 15;
        int sw = n * 16 + (c ^ (n & 7));
        sW[0][sw] = wh[ch];
        sW[1][sw] = wl[ch];
    }
    #pragma unroll
    for (int i = 0; i < 8; ++i) {
        int ch = i * 512 + t;           // 0..4095
        int row = ch >> 4, c = ch & 15;
        int grow = row0 + row; if (grow >= NN) grow = NN - 1;
        f16x8 v;
        if (FP32IN) {
            const float* xp = (const float*)in0 + (size_t)grow * H + c * 8;
            #pragma unroll
            for (int u = 0; u < 8; ++u) v[u] = (f16)xp[u];
        } else {
            v = *((const f16x8*)in0 + (size_t)grow * 16 + c);
            if (in1) {
                f16x8 uu = *((const f16x8*)in1 + (size_t)grow * 16 + c);
                v = v + uu;
            }
        }
        sA[row * 16 + (c ^ (row & 7))] = v;
    }
    __syncthreads();

    int l = t & 63, w = t >> 6;
    int lr = l & 15, lq = l >> 4;
    f16x8 aF[2][4];
    #pragma unroll
    for (int rt = 0; rt < 2; ++rt) {
        int row = w * 32 + rt * 16 + lr;
        #pragma unroll
        for (int ks = 0; ks < 4; ++ks) {
            int c = ks * 4 + lq;
            aF[rt][ks] = sA[row * 16 + (c ^ (row & 7))];
        }
    }
    f32x4 acc[2][8];
    #pragma unroll
    for (int rt = 0; rt < 2; ++rt)
        #pragma unroll
        for (int ct = 0; ct < 8; ++ct)
            acc[rt][ct] = (f32x4){0.f, 0.f, 0.f, 0.f};

    #pragma unroll
    for (int p = 0; p < 2; ++p) {
        #pragma unroll
        for (int ks = 0; ks < 4; ++ks) {
            #pragma unroll
            for (int ct = 0; ct < 8; ++ct) {
                int n = ct * 16 + lr;
                int c = ks * 4 + lq;
                f16x8 bF = sW[p][n * 16 + (c ^ (n & 7))];
                acc[0][ct] = __builtin_amdgcn_mfma_f32_16x16x32_f16(aF[0][ks], bF, acc[0][ct], 0, 0, 0);
                acc[1][ct] = __builtin_amdgcn_mfma_f32_16x16x32_f16(aF[1][ks], bF, acc[1][ct], 0, 0, 0);
            }
        }
    }
    __syncthreads();
    // bounce accumulators through LDS (fp16) for coalesced global stores
    f16* sAh = (f16*)sA;
    #pragma unroll
    for (int rt = 0; rt < 2; ++rt) {
        #pragma unroll
        for (int ct = 0; ct < 8; ++ct) {
            int col = ct * 16 + lr;
            #pragma unroll
            for (int r = 0; r < 4; ++r) {
                int row = w * 32 + rt * 16 + lq * 4 + r;
                sAh[row * H + (((col >> 3) ^ (row & 7)) << 3) + (col & 7)] = (f16)acc[rt][ct][r];
            }
        }
    }
    __syncthreads();
    f16x8* hwv = (f16x8*)hw;
    #pragma unroll
    for (int i = 0; i < 8; ++i) {
        int ch = i * 512 + t;
        int row = ch >> 4, c = ch & 15;
        int grow = row0 + row;
        if (grow < NN) hwv[(size_t)grow * 16 + c] = sA[row * 16 + (c ^ (row & 7))];
    }
}

// ---------------------------------------------------------------- aggregation (fp16 out)
__global__ __launch_bounds__(256) void agg_kernel(const f16* __restrict__ hw,
                                                  const float* __restrict__ dis,
                                                  const int* __restrict__ offs,
                                                  const int2* __restrict__ edata,
                                                  const float* __restrict__ bias,
                                                  f16* __restrict__ outh) {
    int wid  = threadIdx.x >> 6;
    int lane = threadIdx.x & 63;
    int node = blockIdx.x * 4 + wid;
    if (node >= NN) return;
    int q  = lane >> 4;
    int j8 = (lane & 15) * 8;
    int beg = offs[node], end = offs[node + 1];
    int nk = end - beg;
    float acc[8];
    #pragma unroll
    for (int u = 0; u < 8; ++u) acc[u] = 0.f;

    for (int k0 = 0; k0 < nk; k0 += 4) {
        int kk = k0 + q;
        int s = 0; float c = 0.f;
        if (kk < nk) {
            int2 e = edata[beg + kk];
            s = e.x & 0x1FFFF;
            c = __int_as_float(e.y);
        }
        f16x8 v = *(const f16x8*)&hw[(size_t)s * H + j8];
        #pragma unroll
        for (int u = 0; u < 8; ++u) acc[u] += c * (float)v[u];
    }
    float dv = dis[node];
    f16x8 hv = *(const f16x8*)&hw[(size_t)node * H + j8];
    if (q == 0) {
        float sc = dv * dv;
        #pragma unroll
        for (int u = 0; u < 8; ++u) acc[u] += sc * (float)hv[u];
    }
    #pragma unroll
    for (int u = 0; u < 8; ++u) {
        acc[u] += __shfl_xor(acc[u], 16, 64);
        acc[u] += __shfl_xor(acc[u], 32, 64);
    }
    if (q == 0) {
        f16x8 o;
        #pragma unroll
        for (int u = 0; u < 8; ++u) o[u] = (f16)fmaxf(acc[u] + bias[j8 + u], 0.f);
        *(f16x8*)&outh[(size_t)node * H + j8] = o;
    }
}

// ---------------------------------------------------------------- mean-pool + linear head
__global__ __launch_bounds__(128) void pool_kernel(const f16* __restrict__ h,
                                                   const int* __restrict__ batch,
                                                   const float* __restrict__ linW,
                                                   const float* __restrict__ linb,
                                                   float* __restrict__ out) {
    __shared__ float pld[H];
    int g = blockIdx.x;
    int t = threadIdx.x;
    int lo = lower_bound_i(batch, NN, g);
    int hi = lower_bound_i(batch, NN, g + 1);
    float sum = 0.f;
    #pragma unroll 4
    for (int n = lo; n < hi; ++n) sum += (float)h[(size_t)n * H + t];
    float cnt = (float)(hi - lo);
    pld[t] = sum / fmaxf(cnt, 1.0f);
    __syncthreads();
    if (t < NC) {
        float acc = linb[t];
        #pragma unroll 4
        for (int j = 0; j < H; ++j) acc += pld[j] * linW[j * NC + t];
        out[g * NC + t] = acc;
    }
}

// ---------------------------------------------------------------- launch
extern "C" void kernel_launch(void* const* d_in, const int* in_sizes, int n_in,
                              void* d_out, int out_size, void* d_ws, size_t ws_size,
                              hipStream_t stream) {
    const float* x     = (const float*)d_in[0];
    const int*   ei    = (const int*)d_in[1];
    const int*   batch = (const int*)d_in[2];
    const float* W0    = (const float*)d_in[3];
    const float* b0    = (const float*)d_in[4];
    const float* Ws    = (const float*)d_in[5];
    const float* bs    = (const float*)d_in[6];
    const float* linW  = (const float*)d_in[7];
    const float* linb  = (const float*)d_in[8];
    const int* src = ei;
    const int* dst = ei + NE;

    char* p = (char*)d_ws;
    auto alloc = [&](size_t bytes) -> void* {
        void* r = (void*)p;
        p += (bytes + 255) & ~(size_t)255;
        return r;
    };
    f16*   buf0   = (f16*)alloc((size_t)NN * H * 2);
    f16*   buf1   = (f16*)alloc((size_t)NN * H * 2);
    f16*   buf2   = (f16*)alloc((size_t)NN * H * 2);
    f16*   hwb    = (f16*)alloc((size_t)NN * H * 2);
    f16*   wt_hi  = (f16*)alloc((size_t)4 * H * H * 2);
    f16*   wt_lo  = (f16*)alloc((size_t)4 * H * H * 2);
    float* dis    = (float*)alloc((size_t)NN * 4);
    int*   deg    = (int*)alloc((size_t)NN * 4);
    int*   offs   = (int*)alloc((size_t)(NN + 1) * 4);
    int2*  binned = (int2*)alloc((size_t)NE * 8);
    int2*  edata  = (int2*)alloc((size_t)NE * 8);
    int*   psum   = (int*)alloc((size_t)SCAN_B * 4);
    int*   poff   = (int*)alloc((size_t)(SCAN_B + 1) * 4);
    int*   bcur   = (int*)alloc((size_t)NBUCK * 4);

    hipMemsetAsync(deg, 0, (size_t)NN * 4, stream);

    deg_kernel<<<(NE + 255) / 256, 256, 0, stream>>>(dst, deg);
    wprep_kernel<<<(4 * H * H) / 256, 256, 0, stream>>>(W0, Ws, wt_hi, wt_lo);
    scan1_kernel<<<SCAN_B, 256, 0, stream>>>(deg, psum);
    scan2_kernel<<<1, 64, 0, stream>>>(psum, poff, offs, bcur);
    scan3_kernel<<<SCAN_B, 256, 0, stream>>>(deg, poff, offs, dis);
    binA_kernel<<<(NE + CHUNK - 1) / CHUNK, 256, 0, stream>>>(src, dst, dis, bcur, binned);
    binB_kernel<<<NBUCK, 256, 0, stream>>>(binned, poff, offs, edata);

    int gemm_grid = (NN + 255) / 256;
    int agg_grid  = (NN + 3) / 4;
    size_t WSZ = (size_t)H * H;

    gemm_kernel<1><<<gemm_grid, 512, 0, stream>>>(x, nullptr, wt_hi, wt_lo, hwb);
    agg_kernel<<<agg_grid, 256, 0, stream>>>(hwb, dis, offs, edata, b0, buf0);
    gemm_kernel<0><<<gemm_grid, 512, 0, stream>>>(buf0, nullptr, wt_hi + WSZ, wt_lo + WSZ, hwb);
    agg_kernel<<<agg_grid, 256, 0, stream>>>(hwb, dis, offs, edata, bs, buf1);
    gemm_kernel<0><<<gemm_grid, 512, 0, stream>>>(buf1, buf0, wt_hi + 2 * WSZ, wt_lo + 2 * WSZ, hwb);
    agg_kernel<<<agg_grid, 256, 0, stream>>>(hwb, dis, offs, edata, bs + H, buf2);
    gemm_kernel<0><<<gemm_grid, 512, 0, stream>>>(buf2, buf1, wt_hi + 3 * WSZ, wt_lo + 3 * WSZ, hwb);
    agg_kernel<<<agg_grid, 256, 0, stream>>>(hwb, dis, offs, edata, bs + 2 * H, buf0);

    pool_kernel<<<NG, 128, 0, stream>>>(buf0, batch, linW, linb, (float*)d_out);
}

// Round 6
// 536.766 us; speedup vs baseline: 2.2762x; 1.0420x over previous
//
#include <hip/hip_runtime.h>

#define NN 100000
#define NE 1600000
#define H  128
#define NG 512
#define NC 10
#define SCAN_B 98     // ceil(NN/1024) ; also = number of dst buckets (dst>>10)
#define NBUCK  98
#define CHUNK  4096   // edges per pass-A block

typedef _Float16 f16;
typedef __attribute__((ext_vector_type(8))) _Float16 f16x8;
typedef __attribute__((ext_vector_type(4))) float    f32x4;

// ---------------------------------------------------------------- utilities
__device__ __forceinline__ int lower_bound_i(const int* __restrict__ a, int n, int val) {
    int lo = 0, hi = n;
    while (lo < hi) {
        int mid = (lo + hi) >> 1;
        if (a[mid] < val) lo = mid + 1; else hi = mid;
    }
    return lo;
}

// ---------------------------------------------------------------- degree histogram
__global__ __launch_bounds__(256) void deg_kernel(const int* __restrict__ dst,
                                                  int* __restrict__ deg) {
    int e = blockIdx.x * 256 + threadIdx.x;
    if (e < NE) atomicAdd(&deg[dst[e]], 1);
}

// ---------------------------------------------------------------- parallel scan (3 stages)
__global__ __launch_bounds__(256) void scan1_kernel(const int* __restrict__ deg,
                                                    int* __restrict__ psum) {
    int b = blockIdx.x, t = threadIdx.x;
    int i4 = b * 1024 + t * 4;
    int s = 0;
    if (i4 + 3 < NN) {
        int4 v = *(const int4*)&deg[i4];
        s = v.x + v.y + v.z + v.w;
    } else {
        for (int k = 0; k < 4; ++k) if (i4 + k < NN) s += deg[i4 + k];
    }
    #pragma unroll
    for (int d = 32; d; d >>= 1) s += __shfl_down(s, d, 64);
    __shared__ int ws[4];
    if ((t & 63) == 0) ws[t >> 6] = s;
    __syncthreads();
    if (t == 0) psum[b] = ws[0] + ws[1] + ws[2] + ws[3];
}

__global__ void scan2_kernel(const int* __restrict__ psum, int* __restrict__ poff,
                             int* __restrict__ offs, int* __restrict__ bcur) {
    if (threadIdx.x == 0) {
        int run = 0;
        for (int b = 0; b < SCAN_B; ++b) { poff[b] = run; bcur[b] = run; run += psum[b]; }
        poff[SCAN_B] = run;
        offs[NN] = run;
    }
}

__global__ __launch_bounds__(256) void scan3_kernel(const int* __restrict__ deg,
                                                    const int* __restrict__ poff,
                                                    int* __restrict__ offs,
                                                    float* __restrict__ dis) {
    int b = blockIdx.x, t = threadIdx.x;
    int lane = t & 63, wid = t >> 6;
    int i4 = b * 1024 + t * 4;
    int v[4]; int s = 0;
    #pragma unroll
    for (int k = 0; k < 4; ++k) { int i = i4 + k; v[k] = (i < NN) ? deg[i] : 0; s += v[k]; }
    int incl = s;
    #pragma unroll
    for (int d = 1; d < 64; d <<= 1) { int u = __shfl_up(incl, d, 64); if (lane >= d) incl += u; }
    __shared__ int ws[4];
    if (lane == 63) ws[wid] = incl;
    __syncthreads();
    int wbase = 0;
    for (int w = 0; w < wid; ++w) wbase += ws[w];
    int base = poff[b] + wbase + incl - s;
    #pragma unroll
    for (int k = 0; k < 4; ++k) {
        int i = i4 + k;
        if (i < NN) {
            offs[i] = base;
            dis[i] = rsqrtf((float)v[k] + 1.0f);
        }
        base += v[k];
    }
}

// ---------------------------------------------------------------- pass A: bin edges by coarse bucket (dst>>10)
__global__ __launch_bounds__(256) void binA_kernel(const int* __restrict__ src,
                                                   const int* __restrict__ dst,
                                                   const float* __restrict__ dis,
                                                   int* __restrict__ bcur,
                                                   int2* __restrict__ binned) {
    __shared__ int  hist[NBUCK];
    __shared__ int  lbase[NBUCK];
    __shared__ int  gbase[NBUCK];
    __shared__ int  cur[NBUCK];
    __shared__ int2 stage[CHUNK];
    __shared__ int  destp[CHUNK];
    int t  = threadIdx.x;
    int e0 = blockIdx.x * CHUNK;
    int cnt = NE - e0; if (cnt > CHUNK) cnt = CHUNK;

    if (t < NBUCK) hist[t] = 0;
    __syncthreads();

    int s_[16], d_[16];
    #pragma unroll
    for (int i = 0; i < 16; ++i) {
        int e = e0 + i * 256 + t;
        if (e < NE) {
            s_[i] = src[e]; d_[i] = dst[e];
            atomicAdd(&hist[d_[i] >> 10], 1);
        } else { s_[i] = -1; d_[i] = 0; }
    }
    __syncthreads();

    if (t < NBUCK) {
        int lb = 0;
        for (int i = 0; i < t; ++i) lb += hist[i];
        lbase[t] = lb;
        cur[t]   = lb;
        gbase[t] = atomicAdd(&bcur[t], hist[t]);
    }
    __syncthreads();

    #pragma unroll
    for (int i = 0; i < 16; ++i) {
        if (s_[i] >= 0) {
            int s = s_[i], d = d_[i];
            int b = d >> 10;
            int r = atomicAdd(&cur[b], 1);
            float c = dis[s] * dis[d];
            stage[r] = make_int2(s | ((d & 1023) << 17), __float_as_int(c));
            destp[r] = gbase[b] + (r - lbase[b]);
        }
    }
    __syncthreads();

    #pragma unroll
    for (int i = 0; i < 16; ++i) {
        int idx = i * 256 + t;
        if (idx < cnt) binned[destp[idx]] = stage[idx];
    }
}

// ---------------------------------------------------------------- pass B: exact CSR placement within each bucket
__global__ __launch_bounds__(256) void binB_kernel(const int2* __restrict__ binned,
                                                   const int* __restrict__ poff,
                                                   const int* __restrict__ offs,
                                                   int2* __restrict__ edata) {
    __shared__ int cnt1k[1024];
    int b = blockIdx.x, t = threadIdx.x;
    #pragma unroll
    for (int i = 0; i < 4; ++i) cnt1k[t + i * 256] = 0;
    __syncthreads();
    int lo = poff[b], hi = poff[b + 1];
    for (int e = lo + t; e < hi; e += 256) {
        int2 p = binned[e];
        int dloc = (p.x >> 17) & 1023;
        int r = atomicAdd(&cnt1k[dloc], 1);
        int d = (b << 10) + dloc;
        edata[offs[d] + r] = p;
    }
}

// ---------------------------------------------------------------- W split prep: Wt_hi/Wt_lo [4][128][128] fp16, transposed
__global__ __launch_bounds__(256) void wprep_kernel(const float* __restrict__ W0,
                                                    const float* __restrict__ Ws,
                                                    f16* __restrict__ wt_hi,
                                                    f16* __restrict__ wt_lo) {
    int idx = blockIdx.x * 256 + threadIdx.x;   // 4*16384 total
    int m = idx >> 14;
    int k = (idx >> 7) & 127;
    int n = idx & 127;
    const float* Wm = (m == 0) ? W0 : (Ws + (size_t)(m - 1) * H * H);
    float v = Wm[k * H + n];
    f16 hi = (f16)v;
    float lo = v - (float)hi;
    wt_hi[(size_t)m * H * H + n * H + k] = hi;
    wt_lo[(size_t)m * H * H + n * H + k] = (f16)lo;
}

// ---------------------------------------------------------------- MFMA GEMM: hw = fp16((in0 [+ in1]) @ (W_hi + W_lo))
// 256 rows/block, 512 threads (8 waves, 32 rows each). LDS 128 KB.
// frag layout (16x16x32): A/B lane l: dim=l&15, k=(l>>4)*8+j ; D: col=l&15, row=(l>>4)*4+reg
template <int FP32IN>
__global__ __launch_bounds__(512) void gemm_kernel(const void* __restrict__ in0,
                                                   const f16* __restrict__ in1,
                                                   const f16* __restrict__ wt_hi,
                                                   const f16* __restrict__ wt_lo,
                                                   f16* __restrict__ hw) {
    __shared__ f16x8 sA[256 * 16];      // 64 KB, chunk-swizzled (c ^ (row&7))
    __shared__ f16x8 sW[2][128 * 16];   // 64 KB
    int t = threadIdx.x;
    int row0 = blockIdx.x * 256;

    const f16x8* wh = (const f16x8*)wt_hi;
    const f16x8* wl = (const f16x8*)wt_lo;
    #pragma unroll
    for (int i = 0; i < 4; ++i) {
        int ch = i * 512 + t;           // 0..2047
        int n = ch >> 4, c = ch & 15;
        int sw = n * 16 + (c ^ (n & 7));
        sW[0][sw] = wh[ch];
        sW[1][sw] = wl[ch];
    }
    #pragma unroll
    for (int i = 0; i < 8; ++i) {
        int ch = i * 512 + t;           // 0..4095
        int row = ch >> 4, c = ch & 15;
        int grow = row0 + row; if (grow >= NN) grow = NN - 1;
        f16x8 v;
        if (FP32IN) {
            const float* xp = (const float*)in0 + (size_t)grow * H + c * 8;
            #pragma unroll
            for (int u = 0; u < 8; ++u) v[u] = (f16)xp[u];
        } else {
            v = *((const f16x8*)in0 + (size_t)grow * 16 + c);
            if (in1) {
                f16x8 uu = *((const f16x8*)in1 + (size_t)grow * 16 + c);
                v = v + uu;
            }
        }
        sA[row * 16 + (c ^ (row & 7))] = v;
    }
    __syncthreads();

    int l = t & 63, w = t >> 6;
    int lr = l & 15, lq = l >> 4;
    f16x8 aF[2][4];
    #pragma unroll
    for (int rt = 0; rt < 2; ++rt) {
        int row = w * 32 + rt * 16 + lr;
        #pragma unroll
        for (int ks = 0; ks < 4; ++ks) {
            int c = ks * 4 + lq;
            aF[rt][ks] = sA[row * 16 + (c ^ (row & 7))];
        }
    }
    f32x4 acc[2][8];
    #pragma unroll
    for (int rt = 0; rt < 2; ++rt)
        #pragma unroll
        for (int ct = 0; ct < 8; ++ct)
            acc[rt][ct] = (f32x4){0.f, 0.f, 0.f, 0.f};

    #pragma unroll
    for (int p = 0; p < 2; ++p) {
        #pragma unroll
        for (int ks = 0; ks < 4; ++ks) {
            #pragma unroll
            for (int ct = 0; ct < 8; ++ct) {
                int n = ct * 16 + lr;
                int c = ks * 4 + lq;
                f16x8 bF = sW[p][n * 16 + (c ^ (n & 7))];
                acc[0][ct] = __builtin_amdgcn_mfma_f32_16x16x32_f16(aF[0][ks], bF, acc[0][ct], 0, 0, 0);
                acc[1][ct] = __builtin_amdgcn_mfma_f32_16x16x32_f16(aF[1][ks], bF, acc[1][ct], 0, 0, 0);
            }
        }
    }
    __syncthreads();
    // bounce accumulators through LDS (fp16) for coalesced global stores
    f16* sAh = (f16*)sA;
    #pragma unroll
    for (int rt = 0; rt < 2; ++rt) {
        #pragma unroll
        for (int ct = 0; ct < 8; ++ct) {
            int col = ct * 16 + lr;
            #pragma unroll
            for (int r = 0; r < 4; ++r) {
                int row = w * 32 + rt * 16 + lq * 4 + r;
                sAh[row * H + (((col >> 3) ^ (row & 7)) << 3) + (col & 7)] = (f16)acc[rt][ct][r];
            }
        }
    }
    __syncthreads();
    f16x8* hwv = (f16x8*)hw;
    #pragma unroll
    for (int i = 0; i < 8; ++i) {
        int ch = i * 512 + t;
        int row = ch >> 4, c = ch & 15;
        int grow = row0 + row;
        if (grow < NN) hwv[(size_t)grow * 16 + c] = sA[row * 16 + (c ^ (row & 7))];
    }
}

// ---------------------------------------------------------------- aggregation (fp16 out)
// one wave per node; quarter q owns edges k0+q and k0+4+q -> 8 edges in flight per wave
__global__ __launch_bounds__(256) void agg_kernel(const f16* __restrict__ hw,
                                                  const float* __restrict__ dis,
                                                  const int* __restrict__ offs,
                                                  const int2* __restrict__ edata,
                                                  const float* __restrict__ bias,
                                                  f16* __restrict__ outh) {
    int wid  = threadIdx.x >> 6;
    int lane = threadIdx.x & 63;
    int node = blockIdx.x * 4 + wid;
    if (node >= NN) return;
    int q  = lane >> 4;
    int j8 = (lane & 15) * 8;
    int beg = offs[node], end = offs[node + 1];
    int nk = end - beg;
    float acc[8];
    #pragma unroll
    for (int u = 0; u < 8; ++u) acc[u] = 0.f;

    for (int k0 = 0; k0 < nk; k0 += 8) {
        int kA = k0 + q, kB = k0 + 4 + q;
        int sa = 0; float ca = 0.f;
        int sb = 0; float cb = 0.f;
        if (kA < nk) {
            int2 e = edata[beg + kA];
            sa = e.x & 0x1FFFF; ca = __int_as_float(e.y);
        }
        if (kB < nk) {
            int2 e = edata[beg + kB];
            sb = e.x & 0x1FFFF; cb = __int_as_float(e.y);
        }
        f16x8 va = *(const f16x8*)&hw[(size_t)sa * H + j8];
        f16x8 vb = *(const f16x8*)&hw[(size_t)sb * H + j8];
        #pragma unroll
        for (int u = 0; u < 8; ++u) acc[u] += ca * (float)va[u];
        #pragma unroll
        for (int u = 0; u < 8; ++u) acc[u] += cb * (float)vb[u];
    }
    float dv = dis[node];
    f16x8 hv = *(const f16x8*)&hw[(size_t)node * H + j8];
    if (q == 0) {
        float sc = dv * dv;
        #pragma unroll
        for (int u = 0; u < 8; ++u) acc[u] += sc * (float)hv[u];
    }
    #pragma unroll
    for (int u = 0; u < 8; ++u) {
        acc[u] += __shfl_xor(acc[u], 16, 64);
        acc[u] += __shfl_xor(acc[u], 32, 64);
    }
    if (q == 0) {
        f16x8 o;
        #pragma unroll
        for (int u = 0; u < 8; ++u) o[u] = (f16)fmaxf(acc[u] + bias[j8 + u], 0.f);
        *(f16x8*)&outh[(size_t)node * H + j8] = o;
    }
}

// ---------------------------------------------------------------- mean-pool + linear head
__global__ __launch_bounds__(128) void pool_kernel(const f16* __restrict__ h,
                                                   const int* __restrict__ batch,
                                                   const float* __restrict__ linW,
                                                   const float* __restrict__ linb,
                                                   float* __restrict__ out) {
    __shared__ float pld[H];
    int g = blockIdx.x;
    int t = threadIdx.x;
    int lo = lower_bound_i(batch, NN, g);
    int hi = lower_bound_i(batch, NN, g + 1);
    float sum = 0.f;
    #pragma unroll 4
    for (int n = lo; n < hi; ++n) sum += (float)h[(size_t)n * H + t];
    float cnt = (float)(hi - lo);
    pld[t] = sum / fmaxf(cnt, 1.0f);
    __syncthreads();
    if (t < NC) {
        float acc = linb[t];
        #pragma unroll 4
        for (int j = 0; j < H; ++j) acc += pld[j] * linW[j * NC + t];
        out[g * NC + t] = acc;
    }
}

// ---------------------------------------------------------------- launch
extern "C" void kernel_launch(void* const* d_in, const int* in_sizes, int n_in,
                              void* d_out, int out_size, void* d_ws, size_t ws_size,
                              hipStream_t stream) {
    const float* x     = (const float*)d_in[0];
    const int*   ei    = (const int*)d_in[1];
    const int*   batch = (const int*)d_in[2];
    const float* W0    = (const float*)d_in[3];
    const float* b0    = (const float*)d_in[4];
    const float* Ws    = (const float*)d_in[5];
    const float* bs    = (const float*)d_in[6];
    const float* linW  = (const float*)d_in[7];
    const float* linb  = (const float*)d_in[8];
    const int* src = ei;
    const int* dst = ei + NE;

    char* p = (char*)d_ws;
    auto alloc = [&](size_t bytes) -> void* {
        void* r = (void*)p;
        p += (bytes + 255) & ~(size_t)255;
        return r;
    };
    f16*   buf0   = (f16*)alloc((size_t)NN * H * 2);
    f16*   buf1   = (f16*)alloc((size_t)NN * H * 2);
    f16*   buf2   = (f16*)alloc((size_t)NN * H * 2);
    f16*   hwb    = (f16*)alloc((size_t)NN * H * 2);
    f16*   wt_hi  = (f16*)alloc((size_t)4 * H * H * 2);
    f16*   wt_lo  = (f16*)alloc((size_t)4 * H * H * 2);
    float* dis    = (float*)alloc((size_t)NN * 4);
    int*   deg    = (int*)alloc((size_t)NN * 4);
    int*   offs   = (int*)alloc((size_t)(NN + 1) * 4);
    int2*  binned = (int2*)alloc((size_t)NE * 8);
    int2*  edata  = (int2*)alloc((size_t)NE * 8);
    int*   psum   = (int*)alloc((size_t)SCAN_B * 4);
    int*   poff   = (int*)alloc((size_t)(SCAN_B + 1) * 4);
    int*   bcur   = (int*)alloc((size_t)NBUCK * 4);

    hipMemsetAsync(deg, 0, (size_t)NN * 4, stream);

    deg_kernel<<<(NE + 255) / 256, 256, 0, stream>>>(dst, deg);
    wprep_kernel<<<(4 * H * H) / 256, 256, 0, stream>>>(W0, Ws, wt_hi, wt_lo);
    scan1_kernel<<<SCAN_B, 256, 0, stream>>>(deg, psum);
    scan2_kernel<<<1, 64, 0, stream>>>(psum, poff, offs, bcur);
    scan3_kernel<<<SCAN_B, 256, 0, stream>>>(deg, poff, offs, dis);
    binA_kernel<<<(NE + CHUNK - 1) / CHUNK, 256, 0, stream>>>(src, dst, dis, bcur, binned);
    binB_kernel<<<NBUCK, 256, 0, stream>>>(binned, poff, offs, edata);

    int gemm_grid = (NN + 255) / 256;
    int agg_grid  = (NN + 3) / 4;
    size_t WSZ = (size_t)H * H;

    gemm_kernel<1><<<gemm_grid, 512, 0, stream>>>(x, nullptr, wt_hi, wt_lo, hwb);
    agg_kernel<<<agg_grid, 256, 0, stream>>>(hwb, dis, offs, edata, b0, buf0);
    gemm_kernel<0><<<gemm_grid, 512, 0, stream>>>(buf0, nullptr, wt_hi + WSZ, wt_lo + WSZ, hwb);
    agg_kernel<<<agg_grid, 256, 0, stream>>>(hwb, dis, offs, edata, bs, buf1);
    gemm_kernel<0><<<gemm_grid, 512, 0, stream>>>(buf1, buf0, wt_hi + 2 * WSZ, wt_lo + 2 * WSZ, hwb);
    agg_kernel<<<agg_grid, 256, 0, stream>>>(hwb, dis, offs, edata, bs + H, buf2);
    gemm_kernel<0><<<gemm_grid, 512, 0, stream>>>(buf2, buf1, wt_hi + 3 * WSZ, wt_lo + 3 * WSZ, hwb);
    agg_kernel<<<agg_grid, 256, 0, stream>>>(hwb, dis, offs, edata, bs + 2 * H, buf0);

    pool_kernel<<<NG, 128, 0, stream>>>(buf0, batch, linW, linb, (float*)d_out);
}